// Round 1
// baseline (1577.862 us; speedup 1.0000x reference)
//
#include <hip/hip_runtime.h>
#include <hip/hip_bf16.h>

// Sizes (fixed by the problem)
#define B    64
#define P    196      // 14*14
#define DENC 2048
#define AA   512
#define EE   512
#define HH   512
#define VV   10000
#define LL   24
#define TT   23       // L-1

__device__ __forceinline__ float wave_sum(float v) {
    #pragma unroll
    for (int o = 32; o > 0; o >>= 1) v += __shfl_xor(v, o, 64);
    return v;
}
__device__ __forceinline__ float sigmoidf(float x) {
    return 1.0f / (1.0f + __expf(-x));
}

// ---------------- mean over P ----------------
__global__ __launch_bounds__(256) void mean_kernel(const float* __restrict__ enc, float* __restrict__ mean) {
    int b = blockIdx.y;
    int d = blockIdx.x * 256 + threadIdx.x;
    const float* e = enc + (long)b * P * DENC + d;
    float s = 0.f;
    #pragma unroll 4
    for (int p = 0; p < P; ++p) s += e[(long)p * DENC];
    mean[b * DENC + d] = s * (1.0f / (float)P);
}

// ---------------- h0/c0 init: wave per output ----------------
__global__ __launch_bounds__(256) void h0c0_kernel(const float* __restrict__ mean,
                                                   const float* __restrict__ W_h0, const float* __restrict__ b_h0,
                                                   const float* __restrict__ W_c0, const float* __restrict__ b_c0,
                                                   float* __restrict__ h, float* __restrict__ c) {
    int w = blockIdx.x * 4 + (threadIdx.x >> 6);
    int lane = threadIdx.x & 63;
    int sel = w >> 15;            // 0: h0, 1: c0
    int r = w & 32767;
    int j = r >> 6, b = r & 63;   // j-major for W-row L2 reuse
    const float4* mp = (const float4*)(mean + b * DENC);
    const float4* wp = (const float4*)((sel ? W_c0 : W_h0) + (long)j * DENC);
    float s = 0.f;
    for (int i = lane; i < DENC / 4; i += 64) {
        float4 x = mp[i], y = wp[i];
        s += x.x * y.x + x.y * y.y + x.z * y.z + x.w * y.w;
    }
    s = wave_sum(s);
    if (lane == 0) {
        float bias = sel ? b_c0[j] : b_h0[j];
        (sel ? c : h)[b * HH + j] = s + bias;
    }
}

// ---------------- generic fp32 GEMM: C = A(MxK) * B(NxK)^T + bias, optional row mask ----------------
__global__ __launch_bounds__(256) void gemm_f32_kernel(
    const float* __restrict__ A, int lda,
    const float* __restrict__ Bm, int ldb,
    const float* __restrict__ bias,
    float* __restrict__ C, int ldc,
    int M, int N, int K,
    const int* __restrict__ caplen, int Tsteps)
{
    __shared__ float As[16][128];
    __shared__ float Bs[16][128];
    const int bm = blockIdx.y * 128;
    const int bn = blockIdx.x * 128;
    const int tid = threadIdx.x;
    const int tx = tid & 15, ty = tid >> 4;
    float acc[8][8];
    #pragma unroll
    for (int i = 0; i < 8; ++i)
        #pragma unroll
        for (int j = 0; j < 8; ++j) acc[i][j] = 0.f;

    const int lm = tid >> 1;          // 0..127
    const int lk = (tid & 1) * 8;     // 0 or 8

    for (int k0 = 0; k0 < K; k0 += 16) {
        float4 a0 = make_float4(0, 0, 0, 0), a1 = a0, b0 = a0, b1 = a0;
        int gm = bm + lm, gk = k0 + lk;
        if (gm < M) {
            const float* ap = A + (long)gm * lda + gk;
            a0 = *(const float4*)ap; a1 = *(const float4*)(ap + 4);
        }
        int gn = bn + lm;
        if (gn < N) {
            const float* bp = Bm + (long)gn * ldb + gk;
            b0 = *(const float4*)bp; b1 = *(const float4*)(bp + 4);
        }
        __syncthreads();   // previous iter's reads complete
        As[lk + 0][lm] = a0.x; As[lk + 1][lm] = a0.y; As[lk + 2][lm] = a0.z; As[lk + 3][lm] = a0.w;
        As[lk + 4][lm] = a1.x; As[lk + 5][lm] = a1.y; As[lk + 6][lm] = a1.z; As[lk + 7][lm] = a1.w;
        Bs[lk + 0][lm] = b0.x; Bs[lk + 1][lm] = b0.y; Bs[lk + 2][lm] = b0.z; Bs[lk + 3][lm] = b0.w;
        Bs[lk + 4][lm] = b1.x; Bs[lk + 5][lm] = b1.y; Bs[lk + 6][lm] = b1.z; Bs[lk + 7][lm] = b1.w;
        __syncthreads();
        #pragma unroll
        for (int k = 0; k < 16; ++k) {
            float a[8], bb[8];
            #pragma unroll
            for (int i = 0; i < 8; ++i) a[i] = As[k][ty * 8 + i];
            #pragma unroll
            for (int j = 0; j < 8; ++j) bb[j] = Bs[k][tx * 8 + j];
            #pragma unroll
            for (int i = 0; i < 8; ++i)
                #pragma unroll
                for (int j = 0; j < 8; ++j) acc[i][j] += a[i] * bb[j];
        }
    }
    #pragma unroll
    for (int i = 0; i < 8; ++i) {
        int gm = bm + ty * 8 + i;
        if (gm >= M) continue;
        float rowscale = 1.f;
        if (caplen) {
            int b = gm / Tsteps, tt = gm - b * Tsteps;
            if (tt >= caplen[b] - 1) rowscale = 0.f;
        }
        #pragma unroll
        for (int j = 0; j < 8; ++j) {
            int gn = bn + tx * 8 + j;
            if (gn < N) C[(long)gm * ldc + gn] = (acc[i][j] + bias[gn]) * rowscale;
        }
    }
}

// ---------------- hid = h @ W_hid^T + b_hid ----------------
__global__ __launch_bounds__(256) void hid_kernel(const float* __restrict__ h, const float* __restrict__ W,
                                                  const float* __restrict__ bias, float* __restrict__ out) {
    int w = blockIdx.x * 4 + (threadIdx.x >> 6);
    int lane = threadIdx.x & 63;
    int a = w >> 6, b = w & 63;
    const float4* hp = (const float4*)(h + b * HH);
    const float4* wp = (const float4*)(W + (long)a * HH);
    float s = 0.f;
    for (int i = lane; i < HH / 4; i += 64) {
        float4 x = hp[i], y = wp[i];
        s += x.x * y.x + x.y * y.y + x.z * y.z + x.w * y.w;
    }
    s = wave_sum(s);
    if (lane == 0) out[b * AA + a] = s + bias[a];
}

// ---------------- att[b][p] = relu(enc_att[b,p,:]+hid[b,:]) . w_full + b_full ----------------
__global__ __launch_bounds__(256) void att_kernel(const float* __restrict__ enc_att, const float* __restrict__ hid,
                                                  const float* __restrict__ wf, const float* __restrict__ bf,
                                                  float* __restrict__ att) {
    int w = blockIdx.x * 4 + (threadIdx.x >> 6);
    int lane = threadIdx.x & 63;
    int b = w / P, p = w % P;
    const float4* ea = (const float4*)(enc_att + ((long)(b * P + p)) * AA);
    const float4* hp = (const float4*)(hid + b * AA);
    const float4* wp = (const float4*)wf;
    float s = 0.f;
    for (int i = lane; i < AA / 4; i += 64) {
        float4 e = ea[i], hh = hp[i], ww = wp[i];
        float r;
        r = e.x + hh.x; r = r > 0.f ? r : 0.f; s += r * ww.x;
        r = e.y + hh.y; r = r > 0.f ? r : 0.f; s += r * ww.y;
        r = e.z + hh.z; r = r > 0.f ? r : 0.f; s += r * ww.z;
        r = e.w + hh.w; r = r > 0.f ? r : 0.f; s += r * ww.w;
    }
    s = wave_sum(s);
    if (lane == 0) att[b * P + p] = s + bf[0];
}

// ---------------- softmax over P + masked att_weights output ----------------
__global__ __launch_bounds__(256) void softmax_kernel(const float* __restrict__ att, float* __restrict__ aw,
                                                      float* __restrict__ out_att, const int* __restrict__ caplen, int t) {
    int b = blockIdx.x, p = threadIdx.x;
    int wid = p >> 6, lane = p & 63;
    __shared__ float red[4];
    float v = (p < P) ? att[b * P + p] : -1e30f;
    float m = v;
    #pragma unroll
    for (int o = 32; o > 0; o >>= 1) m = fmaxf(m, __shfl_xor(m, o, 64));
    if (lane == 0) red[wid] = m;
    __syncthreads();
    m = fmaxf(fmaxf(red[0], red[1]), fmaxf(red[2], red[3]));
    __syncthreads();
    float e = (p < P) ? __expf(v - m) : 0.f;
    float s = wave_sum(e);
    if (lane == 0) red[wid] = s;
    __syncthreads();
    s = red[0] + red[1] + red[2] + red[3];
    float a = e / s;
    if (p < P) {
        aw[b * P + p] = a;
        bool mask = t < (caplen[b] - 1);
        out_att[((long)b * TT + t) * P + p] = mask ? a : 0.f;
    }
}

// ---------------- ctx[b][d] = sum_p enc[b][p][d]*aw[b][p] ----------------
__global__ __launch_bounds__(256) void ctx_kernel(const float* __restrict__ enc, const float* __restrict__ aw,
                                                  float* __restrict__ ctx) {
    int b = blockIdx.y;
    int d = blockIdx.x * 256 + threadIdx.x;
    __shared__ float awS[P];
    if (threadIdx.x < P) awS[threadIdx.x] = aw[b * P + threadIdx.x];
    __syncthreads();
    const float* e = enc + (long)b * P * DENC + d;
    float s = 0.f;
    #pragma unroll 4
    for (int p = 0; p < P; ++p) s += e[(long)p * DENC] * awS[p];
    ctx[b * DENC + d] = s;
}

// ---------------- gate = sigmoid(h @ W_beta^T + b_beta); ctx *= gate ----------------
__global__ __launch_bounds__(256) void gate_kernel(const float* __restrict__ h, const float* __restrict__ W_beta,
                                                   const float* __restrict__ b_beta, float* __restrict__ ctx) {
    int w = blockIdx.x * 4 + (threadIdx.x >> 6);
    int lane = threadIdx.x & 63;
    int d = w >> 6, b = w & 63;
    const float4* hp = (const float4*)(h + b * HH);
    const float4* wp = (const float4*)(W_beta + (long)d * HH);
    float s = 0.f;
    for (int i = lane; i < HH / 4; i += 64) {
        float4 x = hp[i], y = wp[i];
        s += x.x * y.x + x.y * y.y + x.z * y.z + x.w * y.w;
    }
    s = wave_sum(s);
    if (lane == 0) {
        float g = sigmoidf(s + b_beta[d]);
        ctx[b * DENC + d] *= g;
    }
}

// ---------------- gates[b][g] = emb_t.Wih[:512] + ctx.Wih[512:] + h.Whh + b_ih + b_hh ----------------
__global__ __launch_bounds__(256) void gates_kernel(const float* __restrict__ emb, const int* __restrict__ cap,
                                                    const float* __restrict__ ctx, const float* __restrict__ h,
                                                    const float* __restrict__ W_ih, const float* __restrict__ b_ih,
                                                    const float* __restrict__ W_hh, const float* __restrict__ b_hh,
                                                    float* __restrict__ gates, int t) {
    int w = blockIdx.x * 4 + (threadIdx.x >> 6);
    int lane = threadIdx.x & 63;
    int g = w >> 6, b = w & 63;   // g-major: 64 consecutive waves share W rows (L2)
    const float4* er  = (const float4*)(emb + (long)cap[b * LL + t] * EE);
    const float4* cx  = (const float4*)(ctx + b * DENC);
    const float4* hp  = (const float4*)(h + b * HH);
    const float4* wie = (const float4*)(W_ih + (long)g * (DENC + EE));
    const float4* wic = (const float4*)(W_ih + (long)g * (DENC + EE) + EE);
    const float4* whh = (const float4*)(W_hh + (long)g * HH);
    float s = 0.f;
    for (int i = lane; i < EE / 4; i += 64) {
        float4 x = er[i], y = wie[i];
        s += x.x * y.x + x.y * y.y + x.z * y.z + x.w * y.w;
    }
    for (int i = lane; i < DENC / 4; i += 64) {
        float4 x = cx[i], y = wic[i];
        s += x.x * y.x + x.y * y.y + x.z * y.z + x.w * y.w;
    }
    for (int i = lane; i < HH / 4; i += 64) {
        float4 x = hp[i], y = whh[i];
        s += x.x * y.x + x.y * y.y + x.z * y.z + x.w * y.w;
    }
    s = wave_sum(s);
    if (lane == 0) gates[b * (4 * HH / 2) * 0 + b * 2048 + g] = s + b_ih[g] + b_hh[g];
}

// ---------------- LSTM pointwise + h/c update + Hstore ----------------
__global__ __launch_bounds__(256) void lstm_kernel(const float* __restrict__ gates, float* __restrict__ c,
                                                   float* __restrict__ h, float* __restrict__ Hst,
                                                   const int* __restrict__ caplen, int t) {
    int idx = blockIdx.x * 256 + threadIdx.x;   // 0..32767
    int b = idx >> 9, j = idx & 511;
    const float* g = gates + b * 2048;
    float ig = sigmoidf(g[j]);
    float fg = sigmoidf(g[512 + j]);
    float gg = tanhf(g[1024 + j]);
    float og = sigmoidf(g[1536 + j]);
    float cn = fg * c[idx] + ig * gg;
    float hn = og * tanhf(cn);
    Hst[((long)b * TT + t) * HH + j] = hn;
    bool mask = t < (caplen[b] - 1);
    if (mask) { h[idx] = hn; c[idx] = cn; }
}

// ---------------- meta outputs: captions_gt (as float) + dec_len ----------------
__global__ __launch_bounds__(256) void meta_kernel(const int* __restrict__ cap, const int* __restrict__ caplen,
                                                   float* __restrict__ out_cap, float* __restrict__ out_len) {
    int i = blockIdx.x * 256 + threadIdx.x;
    if (i < B * LL) out_cap[i] = (float)cap[i];
    if (i < B) out_len[i] = (float)(caplen[i] - 1);
}

extern "C" void kernel_launch(void* const* d_in, const int* in_sizes, int n_in,
                              void* d_out, int out_size, void* d_ws, size_t ws_size,
                              hipStream_t stream) {
    const float* enc    = (const float*)d_in[0];
    const int*   cap    = (const int*)d_in[1];
    const int*   caplen = (const int*)d_in[2];
    const float* emb    = (const float*)d_in[3];
    const float* W_enc  = (const float*)d_in[4];
    const float* b_enc  = (const float*)d_in[5];
    const float* W_hid  = (const float*)d_in[6];
    const float* b_hid  = (const float*)d_in[7];
    const float* w_full = (const float*)d_in[8];
    const float* b_full = (const float*)d_in[9];
    const float* W_ih   = (const float*)d_in[10];
    const float* b_ih   = (const float*)d_in[11];
    const float* W_hh   = (const float*)d_in[12];
    const float* b_hh   = (const float*)d_in[13];
    const float* W_h0   = (const float*)d_in[14];
    const float* b_h0   = (const float*)d_in[15];
    const float* W_c0   = (const float*)d_in[16];
    const float* b_c0   = (const float*)d_in[17];
    const float* W_beta = (const float*)d_in[18];
    const float* b_beta = (const float*)d_in[19];
    const float* W_fc   = (const float*)d_in[20];
    const float* b_fc   = (const float*)d_in[21];

    float* out = (float*)d_out;
    float* out_pred = out;                                  // 64*23*10000 = 14,720,000
    float* out_cap  = out + 14720000;                       // 1536
    float* out_len  = out + 14721536;                       // 64
    float* out_att  = out + 14721600;                       // 64*23*196 = 288,512

    float* ws      = (float*)d_ws;
    float* enc_att = ws;                    // 12544*512 = 6,422,528
    float* mean    = enc_att + 6422528;     // 131,072
    float* h       = mean + 131072;         // 32,768
    float* c       = h + 32768;             // 32,768
    float* hid     = c + 32768;             // 32,768
    float* att     = hid + 32768;           // 12,544
    float* aw      = att + 12544;           // 12,544
    float* ctx     = aw + 12544;            // 131,072
    float* gates   = ctx + 131072;          // 131,072
    float* Hst     = gates + 131072;        // 1472*512 = 753,664   (total ~30.7 MB)

    // ---- precompute ----
    mean_kernel<<<dim3(DENC / 256, B), 256, 0, stream>>>(enc, mean);
    h0c0_kernel<<<(2 * B * HH) / 4 / 64, 256, 0, stream>>>(mean, W_h0, b_h0, W_c0, b_c0, h, c);
    // enc_att = enc(12544x2048) @ W_enc(512x2048)^T + b_enc
    gemm_f32_kernel<<<dim3((AA + 127) / 128, (B * P + 127) / 128), 256, 0, stream>>>(
        enc, DENC, W_enc, DENC, b_enc, enc_att, AA, B * P, AA, DENC, nullptr, 0);
    meta_kernel<<<(B * LL + 255) / 256, 256, 0, stream>>>(cap, caplen, out_cap, out_len);

    // ---- recurrent steps ----
    for (int t = 0; t < TT; ++t) {
        hid_kernel<<<(B * AA) / 4 / 64, 256, 0, stream>>>(h, W_hid, b_hid, hid);
        att_kernel<<<(B * P) / 4, 256, 0, stream>>>(enc_att, hid, w_full, b_full, att);
        softmax_kernel<<<B, 256, 0, stream>>>(att, aw, out_att, caplen, t);
        ctx_kernel<<<dim3(DENC / 256, B), 256, 0, stream>>>(enc, aw, ctx);
        gate_kernel<<<(B * DENC) / 4 / 64, 256, 0, stream>>>(h, W_beta, b_beta, ctx);
        gates_kernel<<<(B * 2048) / 4 / 64, 256, 0, stream>>>(emb, cap, ctx, h, W_ih, b_ih, W_hh, b_hh, gates, t);
        lstm_kernel<<<(B * HH) / 256, 256, 0, stream>>>(gates, c, h, Hst, caplen, t);
    }

    // ---- deferred vocab FC: preds = Hst(1472x512) @ W_fc(10000x512)^T + b_fc, masked rows -> 0 ----
    gemm_f32_kernel<<<dim3((VV + 127) / 128, (B * TT + 127) / 128), 256, 0, stream>>>(
        Hst, HH, W_fc, HH, b_fc, out_pred, VV, B * TT, VV, HH, caplen, TT);
}

// Round 2
// 1182.651 us; speedup vs baseline: 1.3342x; 1.3342x over previous
//
#include <hip/hip_runtime.h>
#include <hip/hip_bf16.h>

// Sizes (fixed by the problem)
#define B    64
#define P    196      // 14*14
#define DENC 2048
#define AA   512
#define EE   512
#define HH   512
#define VV   10000
#define LL   24
#define TT   23       // L-1

typedef unsigned short u16;
typedef unsigned int   u32;
typedef __bf16 bf16x8 __attribute__((ext_vector_type(8)));
typedef float  f32x4  __attribute__((ext_vector_type(4)));

__device__ __forceinline__ float wave_sum(float v) {
    #pragma unroll
    for (int o = 32; o > 0; o >>= 1) v += __shfl_xor(v, o, 64);
    return v;
}
__device__ __forceinline__ float sigmoidf(float x) {
    return 1.0f / (1.0f + __expf(-x));
}
// pack two floats -> two bf16 (RNE) in one u32 (little-endian: x in low half)
__device__ __forceinline__ u32 pk2(float x, float y) {
    u32 bx = __float_as_uint(x); bx += 0x7FFFu + ((bx >> 16) & 1u);
    u32 by = __float_as_uint(y); by += 0x7FFFu + ((by >> 16) & 1u);
    return (bx >> 16) | (by & 0xFFFF0000u);
}

// ---------------- mean over P ----------------
__global__ __launch_bounds__(256) void mean_kernel(const float* __restrict__ enc, float* __restrict__ mean) {
    int b = blockIdx.y;
    int d = blockIdx.x * 256 + threadIdx.x;
    const float* e = enc + (long)b * P * DENC + d;
    float s = 0.f;
    #pragma unroll 4
    for (int p = 0; p < P; ++p) s += e[(long)p * DENC];
    mean[b * DENC + d] = s * (1.0f / (float)P);
}

// ---------------- h0/c0 init: wave per output ----------------
__global__ __launch_bounds__(256) void h0c0_kernel(const float* __restrict__ mean,
                                                   const float* __restrict__ W_h0, const float* __restrict__ b_h0,
                                                   const float* __restrict__ W_c0, const float* __restrict__ b_c0,
                                                   float* __restrict__ h, float* __restrict__ c) {
    int w = blockIdx.x * 4 + (threadIdx.x >> 6);
    int lane = threadIdx.x & 63;
    int sel = w >> 15;            // 0: h0, 1: c0
    int r = w & 32767;
    int j = r >> 6, b = r & 63;   // j-major for W-row L2 reuse
    const float4* mp = (const float4*)(mean + b * DENC);
    const float4* wp = (const float4*)((sel ? W_c0 : W_h0) + (long)j * DENC);
    float s = 0.f;
    for (int i = lane; i < DENC / 4; i += 64) {
        float4 x = mp[i], y = wp[i];
        s += x.x * y.x + x.y * y.y + x.z * y.z + x.w * y.w;
    }
    s = wave_sum(s);
    if (lane == 0) {
        float bias = sel ? b_c0[j] : b_h0[j];
        (sel ? c : h)[b * HH + j] = s + bias;
    }
}

// ---------------- bf16 MFMA GEMM: C = A(MxK,f32) * B(NxK,f32)^T + bias ----------------
// 128x128 tile, 4 waves (2x2), each wave 64x64 = 4x4 frags of 16x16x32 MFMA.
// Reg-staging: global f32 -> convert bf16 -> ds_write_b128; frags via ds_read_b128.
__global__ __launch_bounds__(256) void gemm_bf16_kernel(
    const float* __restrict__ A, int lda,
    const float* __restrict__ Bm, int ldb,
    const float* __restrict__ bias,
    float* __restrict__ C, int ldc,
    int M, int N, int K,
    const int* __restrict__ caplen, int Tsteps)
{
    __shared__ __align__(16) u16 As[128 * 32];
    __shared__ __align__(16) u16 Bs[128 * 32];
    const int tid  = threadIdx.x;
    const int lane = tid & 63;
    const int w    = tid >> 6;
    const int wr   = w >> 1, wc = w & 1;
    const int bm = blockIdx.y * 128;
    const int bn = blockIdx.x * 128;

    f32x4 acc[4][4];
    #pragma unroll
    for (int m = 0; m < 4; ++m)
        #pragma unroll
        for (int n = 0; n < 4; ++n) acc[m][n] = (f32x4)0.f;

    // staging: thread -> (row = tid>>1, 16 floats starting at (tid&1)*16)
    const int srow = tid >> 1;
    const int scol = (tid & 1) * 16;
    long arow = bm + srow; if (arow >= M) arow = M - 1;
    long brow = bn + srow; if (brow >= N) brow = N - 1;
    const float* ap = A  + arow * (long)lda + scol;
    const float* bp = Bm + brow * (long)ldb + scol;

    float4 ra[4], rb[4];
    #pragma unroll
    for (int i = 0; i < 4; ++i) { ra[i] = *(const float4*)(ap + 4 * i); rb[i] = *(const float4*)(bp + 4 * i); }

    const int nk = K / 32;
    const int fr = lane & 15;        // frag row/col within 16
    const int kc = (lane >> 4) * 8;  // k-chunk start (bf16 elems)

    for (int kt = 0; kt < nk; ++kt) {
        __syncthreads();   // prior iter's ds_reads complete before overwrite
        uint4 pa0 = make_uint4(pk2(ra[0].x, ra[0].y), pk2(ra[0].z, ra[0].w), pk2(ra[1].x, ra[1].y), pk2(ra[1].z, ra[1].w));
        uint4 pa1 = make_uint4(pk2(ra[2].x, ra[2].y), pk2(ra[2].z, ra[2].w), pk2(ra[3].x, ra[3].y), pk2(ra[3].z, ra[3].w));
        uint4 pb0 = make_uint4(pk2(rb[0].x, rb[0].y), pk2(rb[0].z, rb[0].w), pk2(rb[1].x, rb[1].y), pk2(rb[1].z, rb[1].w));
        uint4 pb1 = make_uint4(pk2(rb[2].x, rb[2].y), pk2(rb[2].z, rb[2].w), pk2(rb[3].x, rb[3].y), pk2(rb[3].z, rb[3].w));
        *(uint4*)&As[srow * 32 + scol]     = pa0;
        *(uint4*)&As[srow * 32 + scol + 8] = pa1;
        *(uint4*)&Bs[srow * 32 + scol]     = pb0;
        *(uint4*)&Bs[srow * 32 + scol + 8] = pb1;
        if (kt + 1 < nk) {   // prefetch next K-tile while LDS settles
            ap += 32; bp += 32;
            #pragma unroll
            for (int i = 0; i < 4; ++i) { ra[i] = *(const float4*)(ap + 4 * i); rb[i] = *(const float4*)(bp + 4 * i); }
        }
        __syncthreads();
        bf16x8 a[4], bfr[4];
        #pragma unroll
        for (int m = 0; m < 4; ++m)
            a[m] = *(const bf16x8*)&As[(wr * 64 + m * 16 + fr) * 32 + kc];
        #pragma unroll
        for (int n = 0; n < 4; ++n)
            bfr[n] = *(const bf16x8*)&Bs[(wc * 64 + n * 16 + fr) * 32 + kc];
        #pragma unroll
        for (int m = 0; m < 4; ++m)
            #pragma unroll
            for (int n = 0; n < 4; ++n)
                acc[m][n] = __builtin_amdgcn_mfma_f32_16x16x32_bf16(a[m], bfr[n], acc[m][n], 0, 0, 0);
    }

    // epilogue: C/D layout col=lane&15, row=(lane>>4)*4+reg
    const int cr = lane >> 4;
    const int cc = lane & 15;
    #pragma unroll
    for (int n = 0; n < 4; ++n) {
        int gn = bn + wc * 64 + n * 16 + cc;
        if (gn >= N) continue;
        float bv = bias[gn];
        #pragma unroll
        for (int m = 0; m < 4; ++m) {
            int gm0 = bm + wr * 64 + m * 16 + cr * 4;
            #pragma unroll
            for (int r = 0; r < 4; ++r) {
                int gm = gm0 + r;
                if (gm >= M) continue;
                float rowscale = 1.f;
                if (caplen) {
                    int b = gm / Tsteps, tt = gm - b * Tsteps;
                    if (tt >= caplen[b] - 1) rowscale = 0.f;
                }
                C[(long)gm * ldc + gn] = (acc[m][n][r] + bv) * rowscale;
            }
        }
    }
}

// ---------------- hid = h @ W_hid^T + b_hid ----------------
__global__ __launch_bounds__(256) void hid_kernel(const float* __restrict__ h, const float* __restrict__ W,
                                                  const float* __restrict__ bias, float* __restrict__ out) {
    int w = blockIdx.x * 4 + (threadIdx.x >> 6);
    int lane = threadIdx.x & 63;
    int a = w >> 6, b = w & 63;
    const float4* hp = (const float4*)(h + b * HH);
    const float4* wp = (const float4*)(W + (long)a * HH);
    float s = 0.f;
    for (int i = lane; i < HH / 4; i += 64) {
        float4 x = hp[i], y = wp[i];
        s += x.x * y.x + x.y * y.y + x.z * y.z + x.w * y.w;
    }
    s = wave_sum(s);
    if (lane == 0) out[b * AA + a] = s + bias[a];
}

// ---------------- att[b][p] = relu(enc_att[b,p,:]+hid[b,:]) . w_full + b_full ----------------
__global__ __launch_bounds__(256) void att_kernel(const float* __restrict__ enc_att, const float* __restrict__ hid,
                                                  const float* __restrict__ wf, const float* __restrict__ bf,
                                                  float* __restrict__ att) {
    int w = blockIdx.x * 4 + (threadIdx.x >> 6);
    int lane = threadIdx.x & 63;
    int b = w / P, p = w % P;
    const float4* ea = (const float4*)(enc_att + ((long)(b * P + p)) * AA);
    const float4* hp = (const float4*)(hid + b * AA);
    const float4* wp = (const float4*)wf;
    float s = 0.f;
    for (int i = lane; i < AA / 4; i += 64) {
        float4 e = ea[i], hh = hp[i], ww = wp[i];
        float r;
        r = e.x + hh.x; r = r > 0.f ? r : 0.f; s += r * ww.x;
        r = e.y + hh.y; r = r > 0.f ? r : 0.f; s += r * ww.y;
        r = e.z + hh.z; r = r > 0.f ? r : 0.f; s += r * ww.z;
        r = e.w + hh.w; r = r > 0.f ? r : 0.f; s += r * ww.w;
    }
    s = wave_sum(s);
    if (lane == 0) att[b * P + p] = s + bf[0];
}

// ---------------- softmax over P + masked att_weights output ----------------
__global__ __launch_bounds__(256) void softmax_kernel(const float* __restrict__ att, float* __restrict__ aw,
                                                      float* __restrict__ out_att, const int* __restrict__ caplen, int t) {
    int b = blockIdx.x, p = threadIdx.x;
    int wid = p >> 6, lane = p & 63;
    __shared__ float red[4];
    float v = (p < P) ? att[b * P + p] : -1e30f;
    float m = v;
    #pragma unroll
    for (int o = 32; o > 0; o >>= 1) m = fmaxf(m, __shfl_xor(m, o, 64));
    if (lane == 0) red[wid] = m;
    __syncthreads();
    m = fmaxf(fmaxf(red[0], red[1]), fmaxf(red[2], red[3]));
    __syncthreads();
    float e = (p < P) ? __expf(v - m) : 0.f;
    float s = wave_sum(e);
    if (lane == 0) red[wid] = s;
    __syncthreads();
    s = red[0] + red[1] + red[2] + red[3];
    float a = e / s;
    if (p < P) {
        aw[b * P + p] = a;
        bool mask = t < (caplen[b] - 1);
        out_att[((long)b * TT + t) * P + p] = mask ? a : 0.f;
    }
}

// ---------------- ctx[b][d] = sum_p enc[b][p][d]*aw[b][p] ----------------
__global__ __launch_bounds__(256) void ctx_kernel(const float* __restrict__ enc, const float* __restrict__ aw,
                                                  float* __restrict__ ctx) {
    int b = blockIdx.y;
    int d = blockIdx.x * 256 + threadIdx.x;
    __shared__ float awS[P];
    if (threadIdx.x < P) awS[threadIdx.x] = aw[b * P + threadIdx.x];
    __syncthreads();
    const float* e = enc + (long)b * P * DENC + d;
    float s = 0.f;
    #pragma unroll 4
    for (int p = 0; p < P; ++p) s += e[(long)p * DENC] * awS[p];
    ctx[b * DENC + d] = s;
}

// ---------------- gate = sigmoid(h @ W_beta^T + b_beta); ctx *= gate ----------------
__global__ __launch_bounds__(256) void gate_kernel(const float* __restrict__ h, const float* __restrict__ W_beta,
                                                   const float* __restrict__ b_beta, float* __restrict__ ctx) {
    int w = blockIdx.x * 4 + (threadIdx.x >> 6);
    int lane = threadIdx.x & 63;
    int d = w >> 6, b = w & 63;
    const float4* hp = (const float4*)(h + b * HH);
    const float4* wp = (const float4*)(W_beta + (long)d * HH);
    float s = 0.f;
    for (int i = lane; i < HH / 4; i += 64) {
        float4 x = hp[i], y = wp[i];
        s += x.x * y.x + x.y * y.y + x.z * y.z + x.w * y.w;
    }
    s = wave_sum(s);
    if (lane == 0) {
        float g = sigmoidf(s + b_beta[d]);
        ctx[b * DENC + d] *= g;
    }
}

// ---------------- gates[b][g] = emb_t.Wih[:512] + ctx.Wih[512:] + h.Whh + b_ih + b_hh ----------------
__global__ __launch_bounds__(256) void gates_kernel(const float* __restrict__ emb, const int* __restrict__ cap,
                                                    const float* __restrict__ ctx, const float* __restrict__ h,
                                                    const float* __restrict__ W_ih, const float* __restrict__ b_ih,
                                                    const float* __restrict__ W_hh, const float* __restrict__ b_hh,
                                                    float* __restrict__ gates, int t) {
    int w = blockIdx.x * 4 + (threadIdx.x >> 6);
    int lane = threadIdx.x & 63;
    int g = w >> 6, b = w & 63;   // g-major: 64 consecutive waves share W rows (L2)
    const float4* er  = (const float4*)(emb + (long)cap[b * LL + t] * EE);
    const float4* cx  = (const float4*)(ctx + b * DENC);
    const float4* hp  = (const float4*)(h + b * HH);
    const float4* wie = (const float4*)(W_ih + (long)g * (DENC + EE));
    const float4* wic = (const float4*)(W_ih + (long)g * (DENC + EE) + EE);
    const float4* whh = (const float4*)(W_hh + (long)g * HH);
    float s = 0.f;
    for (int i = lane; i < EE / 4; i += 64) {
        float4 x = er[i], y = wie[i];
        s += x.x * y.x + x.y * y.y + x.z * y.z + x.w * y.w;
    }
    for (int i = lane; i < DENC / 4; i += 64) {
        float4 x = cx[i], y = wic[i];
        s += x.x * y.x + x.y * y.y + x.z * y.z + x.w * y.w;
    }
    for (int i = lane; i < HH / 4; i += 64) {
        float4 x = hp[i], y = whh[i];
        s += x.x * y.x + x.y * y.y + x.z * y.z + x.w * y.w;
    }
    s = wave_sum(s);
    if (lane == 0) gates[b * 2048 + g] = s + b_ih[g] + b_hh[g];
}

// ---------------- LSTM pointwise + h/c update + Hstore ----------------
__global__ __launch_bounds__(256) void lstm_kernel(const float* __restrict__ gates, float* __restrict__ c,
                                                   float* __restrict__ h, float* __restrict__ Hst,
                                                   const int* __restrict__ caplen, int t) {
    int idx = blockIdx.x * 256 + threadIdx.x;   // 0..32767
    int b = idx >> 9, j = idx & 511;
    const float* g = gates + b * 2048;
    float ig = sigmoidf(g[j]);
    float fg = sigmoidf(g[512 + j]);
    float gg = tanhf(g[1024 + j]);
    float og = sigmoidf(g[1536 + j]);
    float cn = fg * c[idx] + ig * gg;
    float hn = og * tanhf(cn);
    Hst[((long)b * TT + t) * HH + j] = hn;
    bool mask = t < (caplen[b] - 1);
    if (mask) { h[idx] = hn; c[idx] = cn; }
}

// ---------------- meta outputs: captions_gt (as float) + dec_len ----------------
__global__ __launch_bounds__(256) void meta_kernel(const int* __restrict__ cap, const int* __restrict__ caplen,
                                                   float* __restrict__ out_cap, float* __restrict__ out_len) {
    int i = blockIdx.x * 256 + threadIdx.x;
    if (i < B * LL) out_cap[i] = (float)cap[i];
    if (i < B) out_len[i] = (float)(caplen[i] - 1);
}

extern "C" void kernel_launch(void* const* d_in, const int* in_sizes, int n_in,
                              void* d_out, int out_size, void* d_ws, size_t ws_size,
                              hipStream_t stream) {
    const float* enc    = (const float*)d_in[0];
    const int*   cap    = (const int*)d_in[1];
    const int*   caplen = (const int*)d_in[2];
    const float* emb    = (const float*)d_in[3];
    const float* W_enc  = (const float*)d_in[4];
    const float* b_enc  = (const float*)d_in[5];
    const float* W_hid  = (const float*)d_in[6];
    const float* b_hid  = (const float*)d_in[7];
    const float* w_full = (const float*)d_in[8];
    const float* b_full = (const float*)d_in[9];
    const float* W_ih   = (const float*)d_in[10];
    const float* b_ih   = (const float*)d_in[11];
    const float* W_hh   = (const float*)d_in[12];
    const float* b_hh   = (const float*)d_in[13];
    const float* W_h0   = (const float*)d_in[14];
    const float* b_h0   = (const float*)d_in[15];
    const float* W_c0   = (const float*)d_in[16];
    const float* b_c0   = (const float*)d_in[17];
    const float* W_beta = (const float*)d_in[18];
    const float* b_beta = (const float*)d_in[19];
    const float* W_fc   = (const float*)d_in[20];
    const float* b_fc   = (const float*)d_in[21];

    float* out = (float*)d_out;
    float* out_pred = out;                                  // 64*23*10000 = 14,720,000
    float* out_cap  = out + 14720000;                       // 1536
    float* out_len  = out + 14721536;                       // 64
    float* out_att  = out + 14721600;                       // 64*23*196 = 288,512

    float* ws      = (float*)d_ws;
    float* enc_att = ws;                    // 12544*512 = 6,422,528
    float* mean    = enc_att + 6422528;     // 131,072
    float* h       = mean + 131072;         // 32,768
    float* c       = h + 32768;             // 32,768
    float* hid     = c + 32768;             // 32,768
    float* att     = hid + 32768;           // 12,544
    float* aw      = att + 12544;           // 12,544
    float* ctx     = aw + 12544;            // 131,072
    float* gates   = ctx + 131072;          // 131,072
    float* Hst     = gates + 131072;        // 1472*512 = 753,664   (total ~30.7 MB)

    // ---- precompute ----
    mean_kernel<<<dim3(DENC / 256, B), 256, 0, stream>>>(enc, mean);
    h0c0_kernel<<<(2 * B * HH) / 4 / 64, 256, 0, stream>>>(mean, W_h0, b_h0, W_c0, b_c0, h, c);
    // enc_att = enc(12544x2048) @ W_enc(512x2048)^T + b_enc
    gemm_bf16_kernel<<<dim3(AA / 128, (B * P) / 128), 256, 0, stream>>>(
        enc, DENC, W_enc, DENC, b_enc, enc_att, AA, B * P, AA, DENC, nullptr, 0);
    meta_kernel<<<(B * LL + 255) / 256, 256, 0, stream>>>(cap, caplen, out_cap, out_len);

    // ---- recurrent steps ----
    for (int t = 0; t < TT; ++t) {
        hid_kernel<<<(B * AA) / 4 / 64, 256, 0, stream>>>(h, W_hid, b_hid, hid);
        att_kernel<<<(B * P) / 4, 256, 0, stream>>>(enc_att, hid, w_full, b_full, att);
        softmax_kernel<<<B, 256, 0, stream>>>(att, aw, out_att, caplen, t);
        ctx_kernel<<<dim3(DENC / 256, B), 256, 0, stream>>>(enc, aw, ctx);
        gate_kernel<<<(B * DENC) / 4 / 64, 256, 0, stream>>>(h, W_beta, b_beta, ctx);
        gates_kernel<<<(B * 2048) / 4 / 64, 256, 0, stream>>>(emb, cap, ctx, h, W_ih, b_ih, W_hh, b_hh, gates, t);
        lstm_kernel<<<(B * HH) / 256, 256, 0, stream>>>(gates, c, h, Hst, caplen, t);
    }

    // ---- deferred vocab FC: preds = Hst(1472x512) @ W_fc(10000x512)^T + b_fc, masked rows -> 0 ----
    gemm_bf16_kernel<<<dim3((VV + 127) / 128, (B * TT + 127) / 128), 256, 0, stream>>>(
        Hst, HH, W_fc, HH, b_fc, out_pred, VV, B * TT, VV, HH, caplen, TT);
}